// Round 4
// baseline (1082.516 us; speedup 1.0000x reference)
//
#include <hip/hip_runtime.h>
#include <hip/hip_fp16.h>

#define N_NODES 200000
#define N_EDGES 6400000
#define IN_FEAT 128
#define HIDDEN  16
#define NPAD    200704         // 196 * 1024, scan padding

typedef float v4f __attribute__((ext_vector_type(4)));
typedef _Float16 f16x8 __attribute__((ext_vector_type(8)));
typedef float f32x4 __attribute__((ext_vector_type(4)));

// ---------------- 1. per-node in-degree histogram (global u32 atomics) ----------------

__global__ __launch_bounds__(256) void k_cnt(const int* __restrict__ col,
                                             unsigned* __restrict__ bcnt) {
    const int4* c4 = (const int4*)col;
    const int stride = gridDim.x * 256;
    for (int i = blockIdx.x * 256 + threadIdx.x; i < N_EDGES / 4; i += stride) {
        int4 v = c4[i];
        atomicAdd(&bcnt[v.x], 1u);
        atomicAdd(&bcnt[v.y], 1u);
        atomicAdd(&bcnt[v.z], 1u);
        atomicAdd(&bcnt[v.w], 1u);
    }
}

// ---------------- 2. two-level exclusive scan over NPAD counters ----------------

__global__ __launch_bounds__(1024) void k_scan1(const unsigned* __restrict__ bcnt,
                                                unsigned* __restrict__ bexc,
                                                unsigned* __restrict__ totals) {
    __shared__ unsigned s[1024];
    const int t = threadIdx.x;
    const unsigned i = blockIdx.x * 1024 + t;
    unsigned c = bcnt[i];
    s[t] = c;
    __syncthreads();
    #pragma unroll
    for (int d = 1; d < 1024; d <<= 1) {
        unsigned add = (t >= d) ? s[t - d] : 0u;
        __syncthreads();
        s[t] += add;
        __syncthreads();
    }
    bexc[i] = s[t] - c;
    if (t == 1023) totals[blockIdx.x] = s[t];
}

__global__ __launch_bounds__(256) void k_scan2(const unsigned* __restrict__ totals,
                                               unsigned* __restrict__ base) {
    __shared__ unsigned s[256];
    const int t = threadIdx.x;
    unsigned c = (t < NPAD / 1024) ? totals[t] : 0u;
    s[t] = c;
    __syncthreads();
    #pragma unroll
    for (int d = 1; d < 256; d <<= 1) {
        unsigned add = (t >= d) ? s[t - d] : 0u;
        __syncthreads();
        s[t] += add;
        __syncthreads();
    }
    if (t < NPAD / 1024) base[t] = s[t] - c;
}

// finalize CSR offsets (in-place bexc -> boffs), init bcur, compute dinv
__global__ __launch_bounds__(256) void k_scan3(const unsigned* __restrict__ bcnt,
                                               unsigned* __restrict__ boffs,
                                               unsigned* __restrict__ bcur,
                                               const unsigned* __restrict__ base,
                                               float* __restrict__ dinv) {
    const unsigned i = blockIdx.x * 256 + threadIdx.x;   // < NPAD
    unsigned v = boffs[i] + base[i >> 10];
    boffs[i] = v;
    bcur[i] = v;
    if (i < N_NODES) dinv[i] = rsqrtf((float)bcnt[i] + 1.0f);   // +1 self-loop
}

// ---------------- 3. scatter sources into CSR order (return-atomic) ----------------

__global__ __launch_bounds__(256) void k_bscat(const int* __restrict__ row,
                                               const int* __restrict__ col,
                                               unsigned* __restrict__ bcur,
                                               unsigned* __restrict__ sorted) {
    const int4* c4 = (const int4*)col;
    const int4* r4 = (const int4*)row;
    const int stride = gridDim.x * 256;
    for (int i = blockIdx.x * 256 + threadIdx.x; i < N_EDGES / 4; i += stride) {
        int4 c = c4[i];
        int4 r = r4[i];
        unsigned p0 = atomicAdd(&bcur[c.x], 1u);
        unsigned p1 = atomicAdd(&bcur[c.y], 1u);
        unsigned p2 = atomicAdd(&bcur[c.z], 1u);
        unsigned p3 = atomicAdd(&bcur[c.w], 1u);
        sorted[p0] = (unsigned)r.x;
        sorted[p1] = (unsigned)r.y;
        sorted[p2] = (unsigned)r.z;
        sorted[p3] = (unsigned)r.w;
    }
}

// ---------------- layer-1 GEMM via MFMA: h16 = dinv .* (x @ W1), fp16 ----------------

__global__ __launch_bounds__(256) void k_gemm1(const float* __restrict__ x,
                                               const float* __restrict__ W1,
                                               const float* __restrict__ dinv,
                                               __half* __restrict__ h16) {
    const int wave = (blockIdx.x * 256 + threadIdx.x) >> 6;   // tile id
    const int lane = threadIdx.x & 63;
    const int m16 = lane & 15;
    const int quad = lane >> 4;
    if (wave * 16 >= N_NODES) return;

    f16x8 bf[4];
    #pragma unroll
    for (int kb = 0; kb < 4; ++kb)
        #pragma unroll
        for (int j = 0; j < 8; ++j)
            bf[kb][j] = (_Float16)W1[(kb * 32 + quad * 8 + j) * HIDDEN + m16];

    const int node0 = wave * 16;
    const float* xrow = x + (size_t)(node0 + m16) * IN_FEAT + quad * 8;
    f32x4 acc = {0.f, 0.f, 0.f, 0.f};
    #pragma unroll
    for (int kb = 0; kb < 4; ++kb) {
        const v4f* p = (const v4f*)(xrow + kb * 32);
        v4f u0 = p[0], u1 = p[1];
        f16x8 af;
        af[0] = (_Float16)u0.x; af[1] = (_Float16)u0.y;
        af[2] = (_Float16)u0.z; af[3] = (_Float16)u0.w;
        af[4] = (_Float16)u1.x; af[5] = (_Float16)u1.y;
        af[6] = (_Float16)u1.z; af[7] = (_Float16)u1.w;
        acc = __builtin_amdgcn_mfma_f32_16x16x32_f16(af, bf[kb], acc, 0, 0, 0);
    }
    #pragma unroll
    for (int r = 0; r < 4; ++r) {
        int node = node0 + quad * 4 + r;
        h16[(size_t)node * HIDDEN + m16] = __float2half(dinv[node] * acc[r]);
    }
}

// ------- layer-1 CSR aggregation in registers + fused node2 (no LDS, no atomics) -------
// 8 lanes per node; lane l accumulates features 2l, 2l+1; 4-deep pipelined gather.

__global__ __launch_bounds__(256) void k_agg1(const unsigned* __restrict__ sorted,
                                              const unsigned* __restrict__ boffs,
                                              const unsigned* __restrict__ h16u,
                                              const float* __restrict__ dinv,
                                              const float* __restrict__ b1,
                                              const float* __restrict__ W2,
                                              float* __restrict__ tp) {
    const unsigned tid = blockIdx.x * 256 + threadIdx.x;
    const unsigned node = tid >> 3;
    const int l = tid & 7;
    if (node >= N_NODES) return;

    unsigned e = boffs[node];
    const unsigned o1 = boffs[node + 1];
    float ax = 0.f, ay = 0.f;

    unsigned n0 = 0, n1 = 0, n2 = 0, n3 = 0;
    bool have = (e + 4 <= o1);
    if (have) { n0 = sorted[e]; n1 = sorted[e + 1]; n2 = sorted[e + 2]; n3 = sorted[e + 3]; }
    while (have) {
        unsigned c0 = n0, c1 = n1, c2 = n2, c3 = n3;
        e += 4;
        have = (e + 4 <= o1);
        if (have) { n0 = sorted[e]; n1 = sorted[e + 1]; n2 = sorted[e + 2]; n3 = sorted[e + 3]; }
        unsigned v0 = h16u[(size_t)c0 * 8 + l];
        unsigned v1 = h16u[(size_t)c1 * 8 + l];
        unsigned v2 = h16u[(size_t)c2 * 8 + l];
        unsigned v3 = h16u[(size_t)c3 * 8 + l];
        float2 f0 = __half22float2(*(const __half2*)&v0);
        float2 f1 = __half22float2(*(const __half2*)&v1);
        float2 f2 = __half22float2(*(const __half2*)&v2);
        float2 f3 = __half22float2(*(const __half2*)&v3);
        ax += f0.x + f1.x; ay += f0.y + f1.y;
        ax += f2.x + f3.x; ay += f2.y + f3.y;
    }
    for (; e < o1; ++e) {
        unsigned s = sorted[e];
        unsigned v = h16u[(size_t)s * 8 + l];
        float2 f = __half22float2(*(const __half2*)&v);
        ax += f.x; ay += f.y;
    }

    // self-loop + node2 epilogue
    unsigned vs = h16u[(size_t)node * 8 + l];
    float2 fs = __half22float2(*(const __half2*)&vs);
    float di = dinv[node];
    float px = fmaf(di, ax + fs.x, b1[2 * l]);
    float py = fmaf(di, ay + fs.y, b1[2 * l + 1]);
    float r = fmaxf(px, 0.f) * W2[2 * l] + fmaxf(py, 0.f) * W2[2 * l + 1];
    r += __shfl_xor(r, 4, 8);
    r += __shfl_xor(r, 2, 8);
    r += __shfl_xor(r, 1, 8);
    if (l == 0) tp[node] = di * r;
}

// ------- layer-2 CSR aggregation (1 lane/node) + fused finalize -------

__global__ __launch_bounds__(256) void k_agg2(const unsigned* __restrict__ sorted,
                                              const unsigned* __restrict__ boffs,
                                              const float* __restrict__ tp,
                                              const float* __restrict__ dinv,
                                              const float* __restrict__ b2,
                                              float* __restrict__ out) {
    const unsigned node = blockIdx.x * 256 + threadIdx.x;
    if (node >= N_NODES) return;

    unsigned e = boffs[node];
    const unsigned o1 = boffs[node + 1];
    float acc = 0.f;

    unsigned n0 = 0, n1 = 0, n2 = 0, n3 = 0;
    bool have = (e + 4 <= o1);
    if (have) { n0 = sorted[e]; n1 = sorted[e + 1]; n2 = sorted[e + 2]; n3 = sorted[e + 3]; }
    while (have) {
        unsigned c0 = n0, c1 = n1, c2 = n2, c3 = n3;
        e += 4;
        have = (e + 4 <= o1);
        if (have) { n0 = sorted[e]; n1 = sorted[e + 1]; n2 = sorted[e + 2]; n3 = sorted[e + 3]; }
        float t0 = tp[c0];
        float t1 = tp[c1];
        float t2 = tp[c2];
        float t3 = tp[c3];
        acc += t0 + t1;
        acc += t2 + t3;
    }
    for (; e < o1; ++e) acc += tp[sorted[e]];

    out[node] = fmaf(dinv[node], tp[node] + acc, b2[0]);
}

// ---------------- launch ----------------

extern "C" void kernel_launch(void* const* d_in, const int* in_sizes, int n_in,
                              void* d_out, int out_size, void* d_ws, size_t ws_size,
                              hipStream_t stream) {
    const float* x   = (const float*)d_in[0];
    const int*   ei  = (const int*)d_in[1];
    const float* W1  = (const float*)d_in[2];
    const float* b1  = (const float*)d_in[3];
    const float* W2  = (const float*)d_in[4];
    const float* b2  = (const float*)d_in[5];
    float* out = (float*)d_out;

    const int* row = ei;               // sources
    const int* col = ei + N_EDGES;     // targets

    // ws: [bcnt NPAD][boffs NPAD][bcur NPAD][totals 256][base 256]
    //     [dinv N f32][tp N f32][h16 16N fp16][sorted E u32]
    unsigned* bcnt   = (unsigned*)d_ws;
    unsigned* boffs  = bcnt + NPAD;
    unsigned* bcur   = boffs + NPAD;
    unsigned* totals = bcur + NPAD;
    unsigned* base   = totals + 256;
    float*    dinv   = (float*)(base + 256);
    float*    tp     = dinv + N_NODES;
    __half*   h16    = (__half*)(tp + N_NODES);
    unsigned* sorted = (unsigned*)(h16 + (size_t)N_NODES * HIDDEN);

    (void)hipMemsetAsync(bcnt, 0, NPAD * sizeof(unsigned), stream);
    k_cnt<<<2048, 256, 0, stream>>>(col, bcnt);
    k_scan1<<<NPAD / 1024, 1024, 0, stream>>>(bcnt, boffs, totals);
    k_scan2<<<1, 256, 0, stream>>>(totals, base);
    k_scan3<<<NPAD / 256, 256, 0, stream>>>(bcnt, boffs, bcur, base, dinv);
    k_bscat<<<2048, 256, 0, stream>>>(row, col, bcur, sorted);
    k_gemm1<<<(N_NODES / 16 + 3) / 4, 256, 0, stream>>>(x, W1, dinv, h16);
    k_agg1<<<(N_NODES * 8) / 256 + 1, 256, 0, stream>>>(sorted, boffs, (const unsigned*)h16,
                                                        dinv, b1, W2, tp);
    k_agg2<<<(N_NODES + 255) / 256, 256, 0, stream>>>(sorted, boffs, tp, dinv, b2, out);
}

// Round 5
// 511.559 us; speedup vs baseline: 2.1161x; 2.1161x over previous
//
#include <hip/hip_runtime.h>
#include <hip/hip_fp16.h>

#define N_NODES 200000
#define N_EDGES 6400000
#define IN_FEAT 128
#define HIDDEN  16

// ---- two-pass counting sort: 1563 ranges x 128 nodes; pass-1 packs (local<<18)|src ----
#define RN 128
#define RSHIFT 7
#define NR 1563                // 1563*128 = 200064 >= N_NODES
#define NPAD (NR * RN)         // 200064
#define SRC_MASK 0x3FFFFu     // 18 bits, N_NODES < 262144
#define SB 4096                // edges per pass-1 scatter block
#define CAP 5120               // LDS capacity per range (mean 4095, +16 sigma)

typedef float v4f __attribute__((ext_vector_type(4)));
typedef _Float16 f16x8 __attribute__((ext_vector_type(8)));
typedef float f32x4 __attribute__((ext_vector_type(4)));

// ---------------- 1. per-range edge histogram ----------------

__global__ __launch_bounds__(256) void k_bcnt(const int* __restrict__ col,
                                              unsigned* __restrict__ bcnt) {
    __shared__ unsigned c[NR];
    for (int i = threadIdx.x; i < NR; i += 256) c[i] = 0u;
    __syncthreads();
    const int EPB = N_EDGES / 512;            // 12500
    const int4* c4 = (const int4*)(col + (size_t)blockIdx.x * EPB);
    for (int i = threadIdx.x; i < EPB / 4; i += 256) {
        int4 v = c4[i];
        atomicAdd(&c[(unsigned)v.x >> RSHIFT], 1u);
        atomicAdd(&c[(unsigned)v.y >> RSHIFT], 1u);
        atomicAdd(&c[(unsigned)v.z >> RSHIFT], 1u);
        atomicAdd(&c[(unsigned)v.w >> RSHIFT], 1u);
    }
    __syncthreads();
    for (int i = threadIdx.x; i < NR; i += 256)
        if (c[i]) atomicAdd(&bcnt[i], c[i]);
}

// ------------- 2. exclusive scan over 1563 range counts (1 block) -------------

__global__ __launch_bounds__(1024) void k_scanr(const unsigned* __restrict__ bcnt,
                                                unsigned* __restrict__ boffs_r,
                                                unsigned* __restrict__ bcur_r) {
    __shared__ unsigned s[1024];
    const int t = threadIdx.x;
    unsigned c0 = (2 * t     < NR) ? bcnt[2 * t]     : 0u;
    unsigned c1 = (2 * t + 1 < NR) ? bcnt[2 * t + 1] : 0u;
    unsigned pairsum = c0 + c1;
    s[t] = pairsum;
    __syncthreads();
    #pragma unroll
    for (int d = 1; d < 1024; d <<= 1) {
        unsigned add = (t >= d) ? s[t - d] : 0u;
        __syncthreads();
        s[t] += add;
        __syncthreads();
    }
    unsigned excl = s[t] - pairsum;
    if (2 * t < NR)     { boffs_r[2 * t]     = excl;      bcur_r[2 * t]     = excl; }
    if (2 * t + 1 < NR) { boffs_r[2 * t + 1] = excl + c0; bcur_r[2 * t + 1] = excl + c0; }
    if (t == 1023) boffs_r[NR] = s[t];
}

// ---------------- 3. pass-1 scatter into range segments (dense chunk writes) ----------------

__global__ __launch_bounds__(256) void k_bscat(const int* __restrict__ row,
                                               const int* __restrict__ col,
                                               unsigned* __restrict__ bcur_r,
                                               unsigned* __restrict__ tmp) {
    __shared__ unsigned cnt[NR], gbase[NR], lcur[NR];   // 18.8 KB
    const long long e0 = (long long)blockIdx.x * SB;
    long long rem = (long long)N_EDGES - e0;
    const int n = rem > SB ? SB : (int)rem;   // multiple of 4
    for (int i = threadIdx.x; i < NR; i += 256) { cnt[i] = 0u; lcur[i] = 0u; }
    __syncthreads();
    const int4* c4 = (const int4*)(col + e0);
    for (int i = threadIdx.x; i < n / 4; i += 256) {
        int4 v = c4[i];
        atomicAdd(&cnt[(unsigned)v.x >> RSHIFT], 1u);
        atomicAdd(&cnt[(unsigned)v.y >> RSHIFT], 1u);
        atomicAdd(&cnt[(unsigned)v.z >> RSHIFT], 1u);
        atomicAdd(&cnt[(unsigned)v.w >> RSHIFT], 1u);
    }
    __syncthreads();
    for (int i = threadIdx.x; i < NR; i += 256)
        gbase[i] = cnt[i] ? atomicAdd(&bcur_r[i], cnt[i]) : 0u;
    __syncthreads();
    for (int i = threadIdx.x; i < n; i += 256) {
        unsigned c = (unsigned)col[e0 + i];
        unsigned s = (unsigned)row[e0 + i];
        unsigned r = c >> RSHIFT;
        unsigned pos = gbase[r] + atomicAdd(&lcur[r], 1u);
        tmp[pos] = ((c & (RN - 1u)) << 18) | s;
    }
}

// ------- 4. pass-2: per-range LDS counting sort -> node-CSR + boffs_n + dinv -------

__global__ __launch_bounds__(256) void k_bsort(const unsigned* __restrict__ tmp,
                                               const unsigned* __restrict__ boffs_r,
                                               unsigned* __restrict__ boffs_n,
                                               float* __restrict__ dinv,
                                               unsigned* __restrict__ sorted) {
    __shared__ unsigned ebuf[CAP];            // 20 KB
    __shared__ unsigned obuf[CAP];            // 20 KB
    __shared__ unsigned dcnt[RN], dcur[RN], sscan[RN];
    const int r = blockIdx.x;
    const unsigned lo = boffs_r[r], hi = boffs_r[r + 1];
    const unsigned cnt = hi - lo;
    const unsigned node0 = (unsigned)r * RN;
    if (threadIdx.x < RN) dcnt[threadIdx.x] = 0u;
    __syncthreads();

    const bool fits = (cnt <= CAP);
    if (fits) {
        for (unsigned i = threadIdx.x; i < cnt; i += 256) {
            unsigned p = tmp[lo + i];
            ebuf[i] = p;
            atomicAdd(&dcnt[p >> 18], 1u);
        }
    } else {
        for (unsigned i = threadIdx.x; i < cnt; i += 256)
            atomicAdd(&dcnt[tmp[lo + i] >> 18], 1u);
    }
    __syncthreads();

    // exclusive scan over 128 local-node counts
    unsigned c = 0;
    if (threadIdx.x < RN) { c = dcnt[threadIdx.x]; sscan[threadIdx.x] = c; }
    __syncthreads();
    #pragma unroll
    for (int d = 1; d < RN; d <<= 1) {
        unsigned add = 0;
        if (threadIdx.x < RN && threadIdx.x >= d) add = sscan[threadIdx.x - d];
        __syncthreads();
        if (threadIdx.x < RN) sscan[threadIdx.x] += add;
        __syncthreads();
    }
    if (threadIdx.x < RN) {
        unsigned excl = sscan[threadIdx.x] - c;
        dcur[threadIdx.x] = excl;
        unsigned node = node0 + threadIdx.x;
        boffs_n[node] = lo + excl;
        if (node < N_NODES) dinv[node] = rsqrtf((float)c + 1.0f);   // +1 self-loop
    }
    if (r == NR - 1 && threadIdx.x == 0) boffs_n[NPAD] = hi;
    __syncthreads();

    if (fits) {
        for (unsigned i = threadIdx.x; i < cnt; i += 256) {
            unsigned p = ebuf[i];
            unsigned pos = atomicAdd(&dcur[p >> 18], 1u);
            obuf[pos] = p & SRC_MASK;
        }
        __syncthreads();
        for (unsigned i = threadIdx.x; i < cnt; i += 256)
            sorted[lo + i] = obuf[i];          // coalesced full-line writes
    } else {                                   // never taken for this input; correct anyway
        for (unsigned i = threadIdx.x; i < cnt; i += 256) {
            unsigned p = tmp[lo + i];
            unsigned pos = atomicAdd(&dcur[p >> 18], 1u);
            sorted[lo + pos] = p & SRC_MASK;
        }
    }
}

// ---------------- layer-1 GEMM via MFMA: h16 = dinv .* (x @ W1), fp16 ----------------

__global__ __launch_bounds__(256) void k_gemm1(const float* __restrict__ x,
                                               const float* __restrict__ W1,
                                               const float* __restrict__ dinv,
                                               __half* __restrict__ h16) {
    const int wave = (blockIdx.x * 256 + threadIdx.x) >> 6;   // tile id
    const int lane = threadIdx.x & 63;
    const int m16 = lane & 15;
    const int quad = lane >> 4;
    if (wave * 16 >= N_NODES) return;

    f16x8 bf[4];
    #pragma unroll
    for (int kb = 0; kb < 4; ++kb)
        #pragma unroll
        for (int j = 0; j < 8; ++j)
            bf[kb][j] = (_Float16)W1[(kb * 32 + quad * 8 + j) * HIDDEN + m16];

    const int node0 = wave * 16;
    const float* xrow = x + (size_t)(node0 + m16) * IN_FEAT + quad * 8;
    f32x4 acc = {0.f, 0.f, 0.f, 0.f};
    #pragma unroll
    for (int kb = 0; kb < 4; ++kb) {
        const v4f* p = (const v4f*)(xrow + kb * 32);
        v4f u0 = p[0], u1 = p[1];
        f16x8 af;
        af[0] = (_Float16)u0.x; af[1] = (_Float16)u0.y;
        af[2] = (_Float16)u0.z; af[3] = (_Float16)u0.w;
        af[4] = (_Float16)u1.x; af[5] = (_Float16)u1.y;
        af[6] = (_Float16)u1.z; af[7] = (_Float16)u1.w;
        acc = __builtin_amdgcn_mfma_f32_16x16x32_f16(af, bf[kb], acc, 0, 0, 0);
    }
    #pragma unroll
    for (int r = 0; r < 4; ++r) {
        int node = node0 + quad * 4 + r;
        h16[(size_t)node * HIDDEN + m16] = __float2half(dinv[node] * acc[r]);
    }
}

// ------- layer-1 CSR aggregation in registers + fused node2 (no LDS, no atomics) -------
// 8 lanes per node; lane l accumulates features 2l, 2l+1; 4-deep pipelined gather.

__global__ __launch_bounds__(256) void k_agg1(const unsigned* __restrict__ sorted,
                                              const unsigned* __restrict__ boffs,
                                              const unsigned* __restrict__ h16u,
                                              const float* __restrict__ dinv,
                                              const float* __restrict__ b1,
                                              const float* __restrict__ W2,
                                              float* __restrict__ tp) {
    const unsigned tid = blockIdx.x * 256 + threadIdx.x;
    const unsigned node = tid >> 3;
    const int l = tid & 7;
    if (node >= N_NODES) return;

    unsigned e = boffs[node];
    const unsigned o1 = boffs[node + 1];
    float ax = 0.f, ay = 0.f;

    unsigned n0 = 0, n1 = 0, n2 = 0, n3 = 0;
    bool have = (e + 4 <= o1);
    if (have) { n0 = sorted[e]; n1 = sorted[e + 1]; n2 = sorted[e + 2]; n3 = sorted[e + 3]; }
    while (have) {
        unsigned c0 = n0, c1 = n1, c2 = n2, c3 = n3;
        e += 4;
        have = (e + 4 <= o1);
        if (have) { n0 = sorted[e]; n1 = sorted[e + 1]; n2 = sorted[e + 2]; n3 = sorted[e + 3]; }
        unsigned v0 = h16u[(size_t)c0 * 8 + l];
        unsigned v1 = h16u[(size_t)c1 * 8 + l];
        unsigned v2 = h16u[(size_t)c2 * 8 + l];
        unsigned v3 = h16u[(size_t)c3 * 8 + l];
        float2 f0 = __half22float2(*(const __half2*)&v0);
        float2 f1 = __half22float2(*(const __half2*)&v1);
        float2 f2 = __half22float2(*(const __half2*)&v2);
        float2 f3 = __half22float2(*(const __half2*)&v3);
        ax += f0.x + f1.x; ay += f0.y + f1.y;
        ax += f2.x + f3.x; ay += f2.y + f3.y;
    }
    for (; e < o1; ++e) {
        unsigned s = sorted[e];
        unsigned v = h16u[(size_t)s * 8 + l];
        float2 f = __half22float2(*(const __half2*)&v);
        ax += f.x; ay += f.y;
    }

    // self-loop + node2 epilogue
    unsigned vs = h16u[(size_t)node * 8 + l];
    float2 fs = __half22float2(*(const __half2*)&vs);
    float di = dinv[node];
    float px = fmaf(di, ax + fs.x, b1[2 * l]);
    float py = fmaf(di, ay + fs.y, b1[2 * l + 1]);
    float r = fmaxf(px, 0.f) * W2[2 * l] + fmaxf(py, 0.f) * W2[2 * l + 1];
    r += __shfl_xor(r, 4, 8);
    r += __shfl_xor(r, 2, 8);
    r += __shfl_xor(r, 1, 8);
    if (l == 0) tp[node] = di * r;
}

// ------- layer-2 CSR aggregation (1 lane/node) + fused finalize -------

__global__ __launch_bounds__(256) void k_agg2(const unsigned* __restrict__ sorted,
                                              const unsigned* __restrict__ boffs,
                                              const float* __restrict__ tp,
                                              const float* __restrict__ dinv,
                                              const float* __restrict__ b2,
                                              float* __restrict__ out) {
    const unsigned node = blockIdx.x * 256 + threadIdx.x;
    if (node >= N_NODES) return;

    unsigned e = boffs[node];
    const unsigned o1 = boffs[node + 1];
    float acc = 0.f;

    unsigned n0 = 0, n1 = 0, n2 = 0, n3 = 0;
    bool have = (e + 4 <= o1);
    if (have) { n0 = sorted[e]; n1 = sorted[e + 1]; n2 = sorted[e + 2]; n3 = sorted[e + 3]; }
    while (have) {
        unsigned c0 = n0, c1 = n1, c2 = n2, c3 = n3;
        e += 4;
        have = (e + 4 <= o1);
        if (have) { n0 = sorted[e]; n1 = sorted[e + 1]; n2 = sorted[e + 2]; n3 = sorted[e + 3]; }
        float t0 = tp[c0];
        float t1 = tp[c1];
        float t2 = tp[c2];
        float t3 = tp[c3];
        acc += t0 + t1;
        acc += t2 + t3;
    }
    for (; e < o1; ++e) acc += tp[sorted[e]];

    out[node] = fmaf(dinv[node], tp[node] + acc, b2[0]);
}

// ---------------- launch ----------------

extern "C" void kernel_launch(void* const* d_in, const int* in_sizes, int n_in,
                              void* d_out, int out_size, void* d_ws, size_t ws_size,
                              hipStream_t stream) {
    const float* x   = (const float*)d_in[0];
    const int*   ei  = (const int*)d_in[1];
    const float* W1  = (const float*)d_in[2];
    const float* b1  = (const float*)d_in[3];
    const float* W2  = (const float*)d_in[4];
    const float* b2  = (const float*)d_in[5];
    float* out = (float*)d_out;

    const int* row = ei;               // sources
    const int* col = ei + N_EDGES;     // targets

    // ws: [bcnt_r 2048][boffs_r 2048][bcur_r 2048][boffs_n NPAD+64]
    //     [dinv N f32][tp N f32][h16 16N fp16][tmp E u32][sorted E u32]
    unsigned* bcnt_r  = (unsigned*)d_ws;
    unsigned* boffs_r = bcnt_r + 2048;
    unsigned* bcur_r  = boffs_r + 2048;
    unsigned* boffs_n = bcur_r + 2048;
    float*    dinv    = (float*)(boffs_n + NPAD + 64);
    float*    tp      = dinv + N_NODES;
    __half*   h16     = (__half*)(tp + N_NODES);
    unsigned* tmp     = (unsigned*)(h16 + (size_t)N_NODES * HIDDEN);
    unsigned* sorted  = tmp + N_EDGES;

    (void)hipMemsetAsync(bcnt_r, 0, 2048 * sizeof(unsigned), stream);
    k_bcnt<<<512, 256, 0, stream>>>(col, bcnt_r);
    k_scanr<<<1, 1024, 0, stream>>>(bcnt_r, boffs_r, bcur_r);
    k_bscat<<<(N_EDGES + SB - 1) / SB, 256, 0, stream>>>(row, col, bcur_r, tmp);
    k_bsort<<<NR, 256, 0, stream>>>(tmp, boffs_r, boffs_n, dinv, sorted);
    k_gemm1<<<(N_NODES / 16 + 3) / 4, 256, 0, stream>>>(x, W1, dinv, h16);
    k_agg1<<<(N_NODES * 8) / 256 + 1, 256, 0, stream>>>(sorted, boffs_n, (const unsigned*)h16,
                                                        dinv, b1, W2, tp);
    k_agg2<<<(N_NODES + 255) / 256, 256, 0, stream>>>(sorted, boffs_n, tp, dinv, b2, out);
}

// Round 6
// 442.957 us; speedup vs baseline: 2.4438x; 1.1549x over previous
//
#include <hip/hip_runtime.h>
#include <hip/hip_fp16.h>

#define N_NODES 200000
#define N_EDGES 6400000
#define IN_FEAT 128
#define HIDDEN  16

// ---- hierarchical counting sort ----
// coarse: 98 buckets x 2048 nodes ; fine: 1568 ranges x 128 nodes ; NPAD = 200704
#define RN 128
#define NRF 1568               // fine ranges: 1568*128 = 200704 >= N_NODES
#define NC 98                  // coarse buckets: 98*2048 = 200704
#define CSHIFT 11
#define NPAD (NRF * RN)
#define SRC_MASK 0x3FFFFu      // 18 bits
#define SB1 8192               // edges per coarse-scatter block
#define SB2 8192               // edges per fine-scatter block
#define BPB 9                  // fine-scatter blocks per coarse bucket (9*8192 > mean+32sigma)
#define CAP 5120               // bsort LDS capacity (fine mean 4096, +16 sigma)

typedef float v4f __attribute__((ext_vector_type(4)));
typedef _Float16 f16x8 __attribute__((ext_vector_type(8)));
typedef float f32x4 __attribute__((ext_vector_type(4)));

// ---------------- 1. fine-range histogram (1568 counters) ----------------

__global__ __launch_bounds__(256) void k_fcnt(const int* __restrict__ col,
                                              unsigned* __restrict__ fcnt) {
    __shared__ unsigned c[NRF];
    for (int i = threadIdx.x; i < NRF; i += 256) c[i] = 0u;
    __syncthreads();
    const int EPB = N_EDGES / 512;            // 12500
    const int4* c4 = (const int4*)(col + (size_t)blockIdx.x * EPB);
    for (int i = threadIdx.x; i < EPB / 4; i += 256) {
        int4 v = c4[i];
        atomicAdd(&c[(unsigned)v.x >> 7], 1u);
        atomicAdd(&c[(unsigned)v.y >> 7], 1u);
        atomicAdd(&c[(unsigned)v.z >> 7], 1u);
        atomicAdd(&c[(unsigned)v.w >> 7], 1u);
    }
    __syncthreads();
    for (int i = threadIdx.x; i < NRF; i += 256)
        if (c[i]) atomicAdd(&fcnt[i], c[i]);
}

// ------- 2. exclusive scan over 1568 fine counts; derive coarse offsets -------

__global__ __launch_bounds__(1024) void k_scanr(const unsigned* __restrict__ fcnt,
                                                unsigned* __restrict__ foffs,
                                                unsigned* __restrict__ fcur,
                                                unsigned* __restrict__ coffs,
                                                unsigned* __restrict__ ccur) {
    __shared__ unsigned s[1024];
    const int t = threadIdx.x;
    unsigned c0 = (2 * t     < NRF) ? fcnt[2 * t]     : 0u;
    unsigned c1 = (2 * t + 1 < NRF) ? fcnt[2 * t + 1] : 0u;
    unsigned pairsum = c0 + c1;
    s[t] = pairsum;
    __syncthreads();
    #pragma unroll
    for (int d = 1; d < 1024; d <<= 1) {
        unsigned add = (t >= d) ? s[t - d] : 0u;
        __syncthreads();
        s[t] += add;
        __syncthreads();
    }
    unsigned excl = s[t] - pairsum;
    if (2 * t < NRF)     { foffs[2 * t]     = excl;      fcur[2 * t]     = excl; }
    if (2 * t + 1 < NRF) { foffs[2 * t + 1] = excl + c0; fcur[2 * t + 1] = excl + c0; }
    if (t == 1023) foffs[NRF] = s[t];
    __syncthreads();   // block-level visibility of foffs global writes
    if (t < NC)  { unsigned v = foffs[16 * t]; coffs[t] = v; ccur[t] = v; }
    if (t == NC) coffs[NC] = N_EDGES;
}

// ------- 3. coarse scatter: 98 fat chunks per block (dense line writes) -------

__global__ __launch_bounds__(256) void k_cscat(const int* __restrict__ row,
                                               const int* __restrict__ col,
                                               unsigned* __restrict__ ccur,
                                               unsigned* __restrict__ tmp1) {
    __shared__ unsigned cnt[NC], gbase[NC], lcur[NC];
    const long long e0 = (long long)blockIdx.x * SB1;
    long long rem = (long long)N_EDGES - e0;
    const int n = rem > SB1 ? SB1 : (int)rem;   // multiple of 4
    if (threadIdx.x < NC) { cnt[threadIdx.x] = 0u; lcur[threadIdx.x] = 0u; }
    __syncthreads();
    const int4* c4 = (const int4*)(col + e0);
    for (int i = threadIdx.x; i < n / 4; i += 256) {
        int4 v = c4[i];
        atomicAdd(&cnt[(unsigned)v.x >> CSHIFT], 1u);
        atomicAdd(&cnt[(unsigned)v.y >> CSHIFT], 1u);
        atomicAdd(&cnt[(unsigned)v.z >> CSHIFT], 1u);
        atomicAdd(&cnt[(unsigned)v.w >> CSHIFT], 1u);
    }
    __syncthreads();
    if (threadIdx.x < NC)
        gbase[threadIdx.x] = cnt[threadIdx.x] ? atomicAdd(&ccur[threadIdx.x], cnt[threadIdx.x]) : 0u;
    __syncthreads();
    for (int i = threadIdx.x; i < n; i += 256) {
        unsigned c = (unsigned)col[e0 + i];
        unsigned s = (unsigned)row[e0 + i];
        unsigned b = c >> CSHIFT;
        unsigned pos = gbase[b] + atomicAdd(&lcur[b], 1u);
        tmp1[pos] = ((c & 2047u) << 18) | s;     // (local11<<18)|src
    }
}

// ------- 4. fine scatter within a coarse bucket: 16 fat chunks per block -------

__global__ __launch_bounds__(256) void k_fscat(const unsigned* __restrict__ tmp1,
                                               const unsigned* __restrict__ coffs,
                                               unsigned* __restrict__ fcur,
                                               unsigned* __restrict__ tmp2) {
    __shared__ unsigned cnt[16], gbase[16], lcur[16];
    const int b = blockIdx.x / BPB;
    const int sl = blockIdx.x % BPB;
    const unsigned blo = coffs[b], bhi = coffs[b + 1];
    const unsigned lo = blo + (unsigned)sl * SB2;
    if (lo >= bhi) return;
    const unsigned hi = (lo + SB2 < bhi) ? lo + SB2 : bhi;
    const unsigned n = hi - lo;
    if (threadIdx.x < 16) { cnt[threadIdx.x] = 0u; lcur[threadIdx.x] = 0u; }
    __syncthreads();
    for (unsigned i = threadIdx.x; i < n; i += 256)
        atomicAdd(&cnt[tmp1[lo + i] >> 25], 1u);        // local11>>7 = fine sub-range
    __syncthreads();
    if (threadIdx.x < 16)
        gbase[threadIdx.x] = cnt[threadIdx.x]
            ? atomicAdd(&fcur[16 * b + threadIdx.x], cnt[threadIdx.x]) : 0u;
    __syncthreads();
    for (unsigned i = threadIdx.x; i < n; i += 256) {
        unsigned p = tmp1[lo + i];
        unsigned f = p >> 25;
        unsigned pos = gbase[f] + atomicAdd(&lcur[f], 1u);
        tmp2[pos] = p & 0x01FFFFFFu;                     // (local7<<18)|src
    }
}

// ------- 5. per-fine-range LDS counting sort -> node-CSR + boffs_n + dinv -------

__global__ __launch_bounds__(256) void k_bsort(const unsigned* __restrict__ tmp,
                                               const unsigned* __restrict__ boffs_r,
                                               unsigned* __restrict__ boffs_n,
                                               float* __restrict__ dinv,
                                               unsigned* __restrict__ sorted) {
    __shared__ unsigned ebuf[CAP];            // 20 KB
    __shared__ unsigned obuf[CAP];            // 20 KB
    __shared__ unsigned dcnt[RN], dcur[RN], sscan[RN];
    const int r = blockIdx.x;
    const unsigned lo = boffs_r[r], hi = boffs_r[r + 1];
    const unsigned cnt = hi - lo;
    const unsigned node0 = (unsigned)r * RN;
    if (threadIdx.x < RN) dcnt[threadIdx.x] = 0u;
    __syncthreads();

    const bool fits = (cnt <= CAP);
    if (fits) {
        for (unsigned i = threadIdx.x; i < cnt; i += 256) {
            unsigned p = tmp[lo + i];
            ebuf[i] = p;
            atomicAdd(&dcnt[p >> 18], 1u);
        }
    } else {
        for (unsigned i = threadIdx.x; i < cnt; i += 256)
            atomicAdd(&dcnt[tmp[lo + i] >> 18], 1u);
    }
    __syncthreads();

    unsigned c = 0;
    if (threadIdx.x < RN) { c = dcnt[threadIdx.x]; sscan[threadIdx.x] = c; }
    __syncthreads();
    #pragma unroll
    for (int d = 1; d < RN; d <<= 1) {
        unsigned add = 0;
        if (threadIdx.x < RN && threadIdx.x >= d) add = sscan[threadIdx.x - d];
        __syncthreads();
        if (threadIdx.x < RN) sscan[threadIdx.x] += add;
        __syncthreads();
    }
    if (threadIdx.x < RN) {
        unsigned excl = sscan[threadIdx.x] - c;
        dcur[threadIdx.x] = excl;
        unsigned node = node0 + threadIdx.x;
        boffs_n[node] = lo + excl;
        if (node < N_NODES) dinv[node] = rsqrtf((float)c + 1.0f);   // +1 self-loop
    }
    if (r == NRF - 1 && threadIdx.x == 0) boffs_n[NPAD] = hi;
    __syncthreads();

    if (fits) {
        for (unsigned i = threadIdx.x; i < cnt; i += 256) {
            unsigned p = ebuf[i];
            unsigned pos = atomicAdd(&dcur[p >> 18], 1u);
            obuf[pos] = p & SRC_MASK;
        }
        __syncthreads();
        for (unsigned i = threadIdx.x; i < cnt; i += 256)
            sorted[lo + i] = obuf[i];          // coalesced full-line writes
    } else {                                   // never taken for this input; correct anyway
        for (unsigned i = threadIdx.x; i < cnt; i += 256) {
            unsigned p = tmp[lo + i];
            unsigned pos = atomicAdd(&dcur[p >> 18], 1u);
            sorted[lo + pos] = p & SRC_MASK;
        }
    }
}

// ---------------- layer-1 GEMM via MFMA: h16 = dinv .* (x @ W1), fp16 ----------------

__global__ __launch_bounds__(256) void k_gemm1(const float* __restrict__ x,
                                               const float* __restrict__ W1,
                                               const float* __restrict__ dinv,
                                               __half* __restrict__ h16) {
    const int wave = (blockIdx.x * 256 + threadIdx.x) >> 6;   // tile id
    const int lane = threadIdx.x & 63;
    const int m16 = lane & 15;
    const int quad = lane >> 4;
    if (wave * 16 >= N_NODES) return;

    f16x8 bf[4];
    #pragma unroll
    for (int kb = 0; kb < 4; ++kb)
        #pragma unroll
        for (int j = 0; j < 8; ++j)
            bf[kb][j] = (_Float16)W1[(kb * 32 + quad * 8 + j) * HIDDEN + m16];

    const int node0 = wave * 16;
    const float* xrow = x + (size_t)(node0 + m16) * IN_FEAT + quad * 8;
    f32x4 acc = {0.f, 0.f, 0.f, 0.f};
    #pragma unroll
    for (int kb = 0; kb < 4; ++kb) {
        const v4f* p = (const v4f*)(xrow + kb * 32);
        v4f u0 = p[0], u1 = p[1];
        f16x8 af;
        af[0] = (_Float16)u0.x; af[1] = (_Float16)u0.y;
        af[2] = (_Float16)u0.z; af[3] = (_Float16)u0.w;
        af[4] = (_Float16)u1.x; af[5] = (_Float16)u1.y;
        af[6] = (_Float16)u1.z; af[7] = (_Float16)u1.w;
        acc = __builtin_amdgcn_mfma_f32_16x16x32_f16(af, bf[kb], acc, 0, 0, 0);
    }
    #pragma unroll
    for (int r = 0; r < 4; ++r) {
        int node = node0 + quad * 4 + r;
        h16[(size_t)node * HIDDEN + m16] = __float2half(dinv[node] * acc[r]);
    }
}

// ------- layer-1 CSR aggregation in registers + fused node2 (no LDS, no atomics) -------

__global__ __launch_bounds__(256) void k_agg1(const unsigned* __restrict__ sorted,
                                              const unsigned* __restrict__ boffs,
                                              const unsigned* __restrict__ h16u,
                                              const float* __restrict__ dinv,
                                              const float* __restrict__ b1,
                                              const float* __restrict__ W2,
                                              float* __restrict__ tp) {
    const unsigned tid = blockIdx.x * 256 + threadIdx.x;
    const unsigned node = tid >> 3;
    const int l = tid & 7;
    if (node >= N_NODES) return;

    unsigned e = boffs[node];
    const unsigned o1 = boffs[node + 1];
    float ax = 0.f, ay = 0.f;

    unsigned n0 = 0, n1 = 0, n2 = 0, n3 = 0;
    bool have = (e + 4 <= o1);
    if (have) { n0 = sorted[e]; n1 = sorted[e + 1]; n2 = sorted[e + 2]; n3 = sorted[e + 3]; }
    while (have) {
        unsigned c0 = n0, c1 = n1, c2 = n2, c3 = n3;
        e += 4;
        have = (e + 4 <= o1);
        if (have) { n0 = sorted[e]; n1 = sorted[e + 1]; n2 = sorted[e + 2]; n3 = sorted[e + 3]; }
        unsigned v0 = h16u[(size_t)c0 * 8 + l];
        unsigned v1 = h16u[(size_t)c1 * 8 + l];
        unsigned v2 = h16u[(size_t)c2 * 8 + l];
        unsigned v3 = h16u[(size_t)c3 * 8 + l];
        float2 f0 = __half22float2(*(const __half2*)&v0);
        float2 f1 = __half22float2(*(const __half2*)&v1);
        float2 f2 = __half22float2(*(const __half2*)&v2);
        float2 f3 = __half22float2(*(const __half2*)&v3);
        ax += f0.x + f1.x; ay += f0.y + f1.y;
        ax += f2.x + f3.x; ay += f2.y + f3.y;
    }
    for (; e < o1; ++e) {
        unsigned s = sorted[e];
        unsigned v = h16u[(size_t)s * 8 + l];
        float2 f = __half22float2(*(const __half2*)&v);
        ax += f.x; ay += f.y;
    }

    unsigned vs = h16u[(size_t)node * 8 + l];
    float2 fs = __half22float2(*(const __half2*)&vs);
    float di = dinv[node];
    float px = fmaf(di, ax + fs.x, b1[2 * l]);
    float py = fmaf(di, ay + fs.y, b1[2 * l + 1]);
    float r = fmaxf(px, 0.f) * W2[2 * l] + fmaxf(py, 0.f) * W2[2 * l + 1];
    r += __shfl_xor(r, 4, 8);
    r += __shfl_xor(r, 2, 8);
    r += __shfl_xor(r, 1, 8);
    if (l == 0) tp[node] = di * r;
}

// ------- layer-2 CSR aggregation (1 lane/node) + fused finalize -------

__global__ __launch_bounds__(256) void k_agg2(const unsigned* __restrict__ sorted,
                                              const unsigned* __restrict__ boffs,
                                              const float* __restrict__ tp,
                                              const float* __restrict__ dinv,
                                              const float* __restrict__ b2,
                                              float* __restrict__ out) {
    const unsigned node = blockIdx.x * 256 + threadIdx.x;
    if (node >= N_NODES) return;

    unsigned e = boffs[node];
    const unsigned o1 = boffs[node + 1];
    float acc = 0.f;

    unsigned n0 = 0, n1 = 0, n2 = 0, n3 = 0;
    bool have = (e + 4 <= o1);
    if (have) { n0 = sorted[e]; n1 = sorted[e + 1]; n2 = sorted[e + 2]; n3 = sorted[e + 3]; }
    while (have) {
        unsigned c0 = n0, c1 = n1, c2 = n2, c3 = n3;
        e += 4;
        have = (e + 4 <= o1);
        if (have) { n0 = sorted[e]; n1 = sorted[e + 1]; n2 = sorted[e + 2]; n3 = sorted[e + 3]; }
        float t0 = tp[c0];
        float t1 = tp[c1];
        float t2 = tp[c2];
        float t3 = tp[c3];
        acc += t0 + t1;
        acc += t2 + t3;
    }
    for (; e < o1; ++e) acc += tp[sorted[e]];

    out[node] = fmaf(dinv[node], tp[node] + acc, b2[0]);
}

// ---------------- launch ----------------

extern "C" void kernel_launch(void* const* d_in, const int* in_sizes, int n_in,
                              void* d_out, int out_size, void* d_ws, size_t ws_size,
                              hipStream_t stream) {
    const float* x   = (const float*)d_in[0];
    const int*   ei  = (const int*)d_in[1];
    const float* W1  = (const float*)d_in[2];
    const float* b1  = (const float*)d_in[3];
    const float* W2  = (const float*)d_in[4];
    const float* b2  = (const float*)d_in[5];
    float* out = (float*)d_out;

    const int* row = ei;               // sources
    const int* col = ei + N_EDGES;     // targets

    // ws: [fcnt 2048][foffs 2048][fcur 2048][coffs 128][ccur 128][boffs_n NPAD+64]
    //     [dinv N f32][tp N f32][h16 16N fp16][tmp1 E u32][tmp2 E u32]
    // tmp1 is dead after k_fscat and is reused as the final `sorted` array.
    unsigned* fcnt    = (unsigned*)d_ws;
    unsigned* foffs   = fcnt + 2048;
    unsigned* fcur    = foffs + 2048;
    unsigned* coffs   = fcur + 2048;
    unsigned* ccur    = coffs + 128;
    unsigned* boffs_n = ccur + 128;
    float*    dinv    = (float*)(boffs_n + NPAD + 64);
    float*    tp      = dinv + N_NODES;
    __half*   h16     = (__half*)(tp + N_NODES);
    unsigned* tmp1    = (unsigned*)(h16 + (size_t)N_NODES * HIDDEN);
    unsigned* tmp2    = tmp1 + N_EDGES;
    unsigned* sorted  = tmp1;          // reuse

    (void)hipMemsetAsync(fcnt, 0, 2048 * sizeof(unsigned), stream);
    k_fcnt<<<512, 256, 0, stream>>>(col, fcnt);
    k_scanr<<<1, 1024, 0, stream>>>(fcnt, foffs, fcur, coffs, ccur);
    k_cscat<<<(N_EDGES + SB1 - 1) / SB1, 256, 0, stream>>>(row, col, ccur, tmp1);
    k_fscat<<<NC * BPB, 256, 0, stream>>>(tmp1, coffs, fcur, tmp2);
    k_bsort<<<NRF, 256, 0, stream>>>(tmp2, foffs, boffs_n, dinv, sorted);
    k_gemm1<<<(N_NODES / 16 + 3) / 4, 256, 0, stream>>>(x, W1, dinv, h16);
    k_agg1<<<(N_NODES * 8) / 256 + 1, 256, 0, stream>>>(sorted, boffs_n, (const unsigned*)h16,
                                                        dinv, b1, W2, tp);
    k_agg2<<<(N_NODES + 255) / 256, 256, 0, stream>>>(sorted, boffs_n, tp, dinv, b2, out);
}

// Round 7
// 409.834 us; speedup vs baseline: 2.6414x; 1.0808x over previous
//
#include <hip/hip_runtime.h>
#include <hip/hip_fp16.h>

#define N_NODES 200000
#define N_EDGES 6400000
#define IN_FEAT 128
#define HIDDEN  16

// ---- hierarchical counting sort ----
// coarse: 98 buckets x 2048 nodes ; fine: 1568 ranges x 128 nodes ; NPAD = 200704
#define RN 128
#define NRF 1568               // fine ranges: 1568*128 = 200704 >= N_NODES
#define NC 98                  // coarse buckets: 98*2048 = 200704
#define CSHIFT 11
#define NPAD (NRF * RN)
#define SRC_MASK 0x3FFFFu      // 18 bits
#define SB1 8192               // edges per coarse-scatter block
#define SB2 8192               // edges per fine-scatter block
#define BPB 9                  // fine-scatter blocks per coarse bucket
#define CAP 5120               // bsort LDS capacity (fine mean 4096, +16 sigma)

typedef float v4f __attribute__((ext_vector_type(4)));
typedef _Float16 f16x8 __attribute__((ext_vector_type(8)));
typedef float f32x4 __attribute__((ext_vector_type(4)));

// ---------------- 1. fine-range histogram (1568 counters) ----------------

__global__ __launch_bounds__(512) void k_fcnt(const int* __restrict__ col,
                                              unsigned* __restrict__ fcnt) {
    __shared__ unsigned c[NRF];
    for (int i = threadIdx.x; i < NRF; i += 512) c[i] = 0u;
    __syncthreads();
    const int EPB = N_EDGES / 512;            // 12500
    const int4* c4 = (const int4*)(col + (size_t)blockIdx.x * EPB);
    for (int i = threadIdx.x; i < EPB / 4; i += 512) {
        int4 v = c4[i];
        atomicAdd(&c[(unsigned)v.x >> 7], 1u);
        atomicAdd(&c[(unsigned)v.y >> 7], 1u);
        atomicAdd(&c[(unsigned)v.z >> 7], 1u);
        atomicAdd(&c[(unsigned)v.w >> 7], 1u);
    }
    __syncthreads();
    for (int i = threadIdx.x; i < NRF; i += 512)
        if (c[i]) atomicAdd(&fcnt[i], c[i]);
}

// ------- 2. exclusive scan over 1568 fine counts; derive coarse offsets -------

__global__ __launch_bounds__(1024) void k_scanr(const unsigned* __restrict__ fcnt,
                                                unsigned* __restrict__ foffs,
                                                unsigned* __restrict__ fcur,
                                                unsigned* __restrict__ coffs,
                                                unsigned* __restrict__ ccur) {
    __shared__ unsigned s[1024];
    const int t = threadIdx.x;
    unsigned c0 = (2 * t     < NRF) ? fcnt[2 * t]     : 0u;
    unsigned c1 = (2 * t + 1 < NRF) ? fcnt[2 * t + 1] : 0u;
    unsigned pairsum = c0 + c1;
    s[t] = pairsum;
    __syncthreads();
    #pragma unroll
    for (int d = 1; d < 1024; d <<= 1) {
        unsigned add = (t >= d) ? s[t - d] : 0u;
        __syncthreads();
        s[t] += add;
        __syncthreads();
    }
    unsigned excl = s[t] - pairsum;
    if (2 * t < NRF)     { foffs[2 * t]     = excl;      fcur[2 * t]     = excl; }
    if (2 * t + 1 < NRF) { foffs[2 * t + 1] = excl + c0; fcur[2 * t + 1] = excl + c0; }
    if (t == 1023) foffs[NRF] = s[t];
    __syncthreads();   // block-level visibility of foffs global writes
    if (t < NC)  { unsigned v = foffs[16 * t]; coffs[t] = v; ccur[t] = v; }
    if (t == NC) coffs[NC] = N_EDGES;
}

// ------- 3. coarse scatter: 98 fat chunks per block (dense line writes) -------

__global__ __launch_bounds__(512) void k_cscat(const int* __restrict__ row,
                                               const int* __restrict__ col,
                                               unsigned* __restrict__ ccur,
                                               unsigned* __restrict__ tmp1) {
    __shared__ unsigned cnt[NC], gbase[NC], lcur[NC];
    const long long e0 = (long long)blockIdx.x * SB1;
    long long rem = (long long)N_EDGES - e0;
    const int n = rem > SB1 ? SB1 : (int)rem;   // multiple of 4
    if (threadIdx.x < NC) { cnt[threadIdx.x] = 0u; lcur[threadIdx.x] = 0u; }
    __syncthreads();
    const int4* c4 = (const int4*)(col + e0);
    const int4* r4 = (const int4*)(row + e0);
    for (int i = threadIdx.x; i < n / 4; i += 512) {
        int4 v = c4[i];
        atomicAdd(&cnt[(unsigned)v.x >> CSHIFT], 1u);
        atomicAdd(&cnt[(unsigned)v.y >> CSHIFT], 1u);
        atomicAdd(&cnt[(unsigned)v.z >> CSHIFT], 1u);
        atomicAdd(&cnt[(unsigned)v.w >> CSHIFT], 1u);
    }
    __syncthreads();
    if (threadIdx.x < NC)
        gbase[threadIdx.x] = cnt[threadIdx.x] ? atomicAdd(&ccur[threadIdx.x], cnt[threadIdx.x]) : 0u;
    __syncthreads();
    for (int i = threadIdx.x; i < n / 4; i += 512) {
        int4 c = c4[i];
        int4 r = r4[i];
        unsigned b, pos;
        b = (unsigned)c.x >> CSHIFT; pos = gbase[b] + atomicAdd(&lcur[b], 1u);
        tmp1[pos] = (((unsigned)c.x & 2047u) << 18) | (unsigned)r.x;
        b = (unsigned)c.y >> CSHIFT; pos = gbase[b] + atomicAdd(&lcur[b], 1u);
        tmp1[pos] = (((unsigned)c.y & 2047u) << 18) | (unsigned)r.y;
        b = (unsigned)c.z >> CSHIFT; pos = gbase[b] + atomicAdd(&lcur[b], 1u);
        tmp1[pos] = (((unsigned)c.z & 2047u) << 18) | (unsigned)r.z;
        b = (unsigned)c.w >> CSHIFT; pos = gbase[b] + atomicAdd(&lcur[b], 1u);
        tmp1[pos] = (((unsigned)c.w & 2047u) << 18) | (unsigned)r.w;
    }
}

// ------- 4. fine scatter within a coarse bucket: 16 fat chunks per block -------

__global__ __launch_bounds__(512) void k_fscat(const unsigned* __restrict__ tmp1,
                                               const unsigned* __restrict__ coffs,
                                               unsigned* __restrict__ fcur,
                                               unsigned* __restrict__ tmp2) {
    __shared__ unsigned cnt[16], gbase[16], lcur[16];
    const int b = blockIdx.x / BPB;
    const int sl = blockIdx.x % BPB;
    const unsigned blo = coffs[b], bhi = coffs[b + 1];
    const unsigned lo = blo + (unsigned)sl * SB2;
    if (lo >= bhi) return;
    const unsigned hi = (lo + SB2 < bhi) ? lo + SB2 : bhi;
    const unsigned n = hi - lo;
    if (threadIdx.x < 16) { cnt[threadIdx.x] = 0u; lcur[threadIdx.x] = 0u; }
    __syncthreads();
    for (unsigned i = threadIdx.x; i < n; i += 512)
        atomicAdd(&cnt[tmp1[lo + i] >> 25], 1u);        // local11>>7 = fine sub-range
    __syncthreads();
    if (threadIdx.x < 16)
        gbase[threadIdx.x] = cnt[threadIdx.x]
            ? atomicAdd(&fcur[16 * b + threadIdx.x], cnt[threadIdx.x]) : 0u;
    __syncthreads();
    for (unsigned i = threadIdx.x; i < n; i += 512) {
        unsigned p = tmp1[lo + i];
        unsigned f = p >> 25;
        unsigned pos = gbase[f] + atomicAdd(&lcur[f], 1u);
        tmp2[pos] = p & 0x01FFFFFFu;                     // (local7<<18)|src
    }
}

// ------- 5. per-fine-range LDS counting sort -> node-CSR + boffs_n + dinv -------
// two-pass read of tmp (2nd is L2-hot); obuf only -> 22 KB LDS -> 7 blocks/CU

__global__ __launch_bounds__(256) void k_bsort(const unsigned* __restrict__ tmp,
                                               const unsigned* __restrict__ boffs_r,
                                               unsigned* __restrict__ boffs_n,
                                               float* __restrict__ dinv,
                                               unsigned* __restrict__ sorted) {
    __shared__ unsigned obuf[CAP];            // 20 KB
    __shared__ unsigned dcnt[RN], dcur[RN], sscan[RN];
    const int r = blockIdx.x;
    const unsigned lo = boffs_r[r], hi = boffs_r[r + 1];
    const unsigned cnt = hi - lo;
    const unsigned node0 = (unsigned)r * RN;
    if (threadIdx.x < RN) dcnt[threadIdx.x] = 0u;
    __syncthreads();

    for (unsigned i = threadIdx.x; i < cnt; i += 256)
        atomicAdd(&dcnt[tmp[lo + i] >> 18], 1u);
    __syncthreads();

    unsigned c = 0;
    if (threadIdx.x < RN) { c = dcnt[threadIdx.x]; sscan[threadIdx.x] = c; }
    __syncthreads();
    #pragma unroll
    for (int d = 1; d < RN; d <<= 1) {
        unsigned add = 0;
        if (threadIdx.x < RN && threadIdx.x >= d) add = sscan[threadIdx.x - d];
        __syncthreads();
        if (threadIdx.x < RN) sscan[threadIdx.x] += add;
        __syncthreads();
    }
    if (threadIdx.x < RN) {
        unsigned excl = sscan[threadIdx.x] - c;
        dcur[threadIdx.x] = excl;
        unsigned node = node0 + threadIdx.x;
        boffs_n[node] = lo + excl;
        if (node < N_NODES) dinv[node] = rsqrtf((float)c + 1.0f);   // +1 self-loop
    }
    if (r == NRF - 1 && threadIdx.x == 0) boffs_n[NPAD] = hi;
    __syncthreads();

    if (cnt <= CAP) {
        for (unsigned i = threadIdx.x; i < cnt; i += 256) {
            unsigned p = tmp[lo + i];                    // L2-hot re-read
            unsigned pos = atomicAdd(&dcur[p >> 18], 1u);
            obuf[pos] = p & SRC_MASK;
        }
        __syncthreads();
        for (unsigned i = threadIdx.x; i < cnt; i += 256)
            sorted[lo + i] = obuf[i];                    // coalesced full-line writes
    } else {                                             // never taken for this input
        for (unsigned i = threadIdx.x; i < cnt; i += 256) {
            unsigned p = tmp[lo + i];
            unsigned pos = atomicAdd(&dcur[p >> 18], 1u);
            sorted[lo + pos] = p & SRC_MASK;
        }
    }
}

// ---------------- layer-1 GEMM via MFMA: h16 = dinv .* (x @ W1), fp16 ----------------

__global__ __launch_bounds__(256) void k_gemm1(const float* __restrict__ x,
                                               const float* __restrict__ W1,
                                               const float* __restrict__ dinv,
                                               __half* __restrict__ h16) {
    const int wave = (blockIdx.x * 256 + threadIdx.x) >> 6;   // tile id
    const int lane = threadIdx.x & 63;
    const int m16 = lane & 15;
    const int quad = lane >> 4;
    if (wave * 16 >= N_NODES) return;

    f16x8 bf[4];
    #pragma unroll
    for (int kb = 0; kb < 4; ++kb)
        #pragma unroll
        for (int j = 0; j < 8; ++j)
            bf[kb][j] = (_Float16)W1[(kb * 32 + quad * 8 + j) * HIDDEN + m16];

    const int node0 = wave * 16;
    const float* xrow = x + (size_t)(node0 + m16) * IN_FEAT + quad * 8;
    f32x4 acc = {0.f, 0.f, 0.f, 0.f};
    #pragma unroll
    for (int kb = 0; kb < 4; ++kb) {
        const v4f* p = (const v4f*)(xrow + kb * 32);
        v4f u0 = p[0], u1 = p[1];
        f16x8 af;
        af[0] = (_Float16)u0.x; af[1] = (_Float16)u0.y;
        af[2] = (_Float16)u0.z; af[3] = (_Float16)u0.w;
        af[4] = (_Float16)u1.x; af[5] = (_Float16)u1.y;
        af[6] = (_Float16)u1.z; af[7] = (_Float16)u1.w;
        acc = __builtin_amdgcn_mfma_f32_16x16x32_f16(af, bf[kb], acc, 0, 0, 0);
    }
    #pragma unroll
    for (int r = 0; r < 4; ++r) {
        int node = node0 + quad * 4 + r;
        h16[(size_t)node * HIDDEN + m16] = __float2half(dinv[node] * acc[r]);
    }
}

// ------- layer-1 CSR aggregation in registers + fused node2 (8-deep pipeline) -------

__global__ __launch_bounds__(256) void k_agg1(const unsigned* __restrict__ sorted,
                                              const unsigned* __restrict__ boffs,
                                              const unsigned* __restrict__ h16u,
                                              const float* __restrict__ dinv,
                                              const float* __restrict__ b1,
                                              const float* __restrict__ W2,
                                              float* __restrict__ tp) {
    const unsigned tid = blockIdx.x * 256 + threadIdx.x;
    const unsigned node = tid >> 3;
    const int l = tid & 7;
    if (node >= N_NODES) return;

    unsigned e = boffs[node];
    const unsigned o1 = boffs[node + 1];
    float ax = 0.f, ay = 0.f;

    unsigned n0, n1, n2, n3, n4, n5, n6, n7;
    bool have = (e + 8 <= o1);
    if (have) {
        n0 = sorted[e];     n1 = sorted[e + 1]; n2 = sorted[e + 2]; n3 = sorted[e + 3];
        n4 = sorted[e + 4]; n5 = sorted[e + 5]; n6 = sorted[e + 6]; n7 = sorted[e + 7];
    }
    while (have) {
        unsigned c0 = n0, c1 = n1, c2 = n2, c3 = n3, c4 = n4, c5 = n5, c6 = n6, c7 = n7;
        e += 8;
        have = (e + 8 <= o1);
        if (have) {
            n0 = sorted[e];     n1 = sorted[e + 1]; n2 = sorted[e + 2]; n3 = sorted[e + 3];
            n4 = sorted[e + 4]; n5 = sorted[e + 5]; n6 = sorted[e + 6]; n7 = sorted[e + 7];
        }
        unsigned v0 = h16u[(size_t)c0 * 8 + l];
        unsigned v1 = h16u[(size_t)c1 * 8 + l];
        unsigned v2 = h16u[(size_t)c2 * 8 + l];
        unsigned v3 = h16u[(size_t)c3 * 8 + l];
        unsigned v4 = h16u[(size_t)c4 * 8 + l];
        unsigned v5 = h16u[(size_t)c5 * 8 + l];
        unsigned v6 = h16u[(size_t)c6 * 8 + l];
        unsigned v7 = h16u[(size_t)c7 * 8 + l];
        float2 f0 = __half22float2(*(const __half2*)&v0);
        float2 f1 = __half22float2(*(const __half2*)&v1);
        float2 f2 = __half22float2(*(const __half2*)&v2);
        float2 f3 = __half22float2(*(const __half2*)&v3);
        float2 f4 = __half22float2(*(const __half2*)&v4);
        float2 f5 = __half22float2(*(const __half2*)&v5);
        float2 f6 = __half22float2(*(const __half2*)&v6);
        float2 f7 = __half22float2(*(const __half2*)&v7);
        ax += f0.x + f1.x + f2.x + f3.x;
        ay += f0.y + f1.y + f2.y + f3.y;
        ax += f4.x + f5.x + f6.x + f7.x;
        ay += f4.y + f5.y + f6.y + f7.y;
    }
    for (; e < o1; ++e) {
        unsigned s = sorted[e];
        unsigned v = h16u[(size_t)s * 8 + l];
        float2 f = __half22float2(*(const __half2*)&v);
        ax += f.x; ay += f.y;
    }

    unsigned vs = h16u[(size_t)node * 8 + l];
    float2 fs = __half22float2(*(const __half2*)&vs);
    float di = dinv[node];
    float px = fmaf(di, ax + fs.x, b1[2 * l]);
    float py = fmaf(di, ay + fs.y, b1[2 * l + 1]);
    float r = fmaxf(px, 0.f) * W2[2 * l] + fmaxf(py, 0.f) * W2[2 * l + 1];
    r += __shfl_xor(r, 4, 8);
    r += __shfl_xor(r, 2, 8);
    r += __shfl_xor(r, 1, 8);
    if (l == 0) tp[node] = di * r;
}

// ------- layer-2 CSR aggregation (1 lane/node, 8-deep) + fused finalize -------

__global__ __launch_bounds__(256) void k_agg2(const unsigned* __restrict__ sorted,
                                              const unsigned* __restrict__ boffs,
                                              const float* __restrict__ tp,
                                              const float* __restrict__ dinv,
                                              const float* __restrict__ b2,
                                              float* __restrict__ out) {
    const unsigned node = blockIdx.x * 256 + threadIdx.x;
    if (node >= N_NODES) return;

    unsigned e = boffs[node];
    const unsigned o1 = boffs[node + 1];
    float acc = 0.f;

    unsigned n0, n1, n2, n3, n4, n5, n6, n7;
    bool have = (e + 8 <= o1);
    if (have) {
        n0 = sorted[e];     n1 = sorted[e + 1]; n2 = sorted[e + 2]; n3 = sorted[e + 3];
        n4 = sorted[e + 4]; n5 = sorted[e + 5]; n6 = sorted[e + 6]; n7 = sorted[e + 7];
    }
    while (have) {
        unsigned c0 = n0, c1 = n1, c2 = n2, c3 = n3, c4 = n4, c5 = n5, c6 = n6, c7 = n7;
        e += 8;
        have = (e + 8 <= o1);
        if (have) {
            n0 = sorted[e];     n1 = sorted[e + 1]; n2 = sorted[e + 2]; n3 = sorted[e + 3];
            n4 = sorted[e + 4]; n5 = sorted[e + 5]; n6 = sorted[e + 6]; n7 = sorted[e + 7];
        }
        float t0 = tp[c0], t1 = tp[c1], t2 = tp[c2], t3 = tp[c3];
        float t4 = tp[c4], t5 = tp[c5], t6 = tp[c6], t7 = tp[c7];
        acc += t0 + t1 + t2 + t3;
        acc += t4 + t5 + t6 + t7;
    }
    for (; e < o1; ++e) acc += tp[sorted[e]];

    out[node] = fmaf(dinv[node], tp[node] + acc, b2[0]);
}

// ---------------- launch ----------------

extern "C" void kernel_launch(void* const* d_in, const int* in_sizes, int n_in,
                              void* d_out, int out_size, void* d_ws, size_t ws_size,
                              hipStream_t stream) {
    const float* x   = (const float*)d_in[0];
    const int*   ei  = (const int*)d_in[1];
    const float* W1  = (const float*)d_in[2];
    const float* b1  = (const float*)d_in[3];
    const float* W2  = (const float*)d_in[4];
    const float* b2  = (const float*)d_in[5];
    float* out = (float*)d_out;

    const int* row = ei;               // sources
    const int* col = ei + N_EDGES;     // targets

    // ws: [fcnt 2048][foffs 2048][fcur 2048][coffs 128][ccur 128][boffs_n NPAD+64]
    //     [dinv N f32][tp N f32][h16 16N fp16][tmp1 E u32][tmp2 E u32]
    // tmp1 is dead after k_fscat and is reused as the final `sorted` array.
    unsigned* fcnt    = (unsigned*)d_ws;
    unsigned* foffs   = fcnt + 2048;
    unsigned* fcur    = foffs + 2048;
    unsigned* coffs   = fcur + 2048;
    unsigned* ccur    = coffs + 128;
    unsigned* boffs_n = ccur + 128;
    float*    dinv    = (float*)(boffs_n + NPAD + 64);
    float*    tp      = dinv + N_NODES;
    __half*   h16     = (__half*)(tp + N_NODES);
    unsigned* tmp1    = (unsigned*)(h16 + (size_t)N_NODES * HIDDEN);
    unsigned* tmp2    = tmp1 + N_EDGES;
    unsigned* sorted  = tmp1;          // reuse

    (void)hipMemsetAsync(fcnt, 0, 2048 * sizeof(unsigned), stream);
    k_fcnt<<<512, 512, 0, stream>>>(col, fcnt);
    k_scanr<<<1, 1024, 0, stream>>>(fcnt, foffs, fcur, coffs, ccur);
    k_cscat<<<(N_EDGES + SB1 - 1) / SB1, 512, 0, stream>>>(row, col, ccur, tmp1);
    k_fscat<<<NC * BPB, 512, 0, stream>>>(tmp1, coffs, fcur, tmp2);
    k_bsort<<<NRF, 256, 0, stream>>>(tmp2, foffs, boffs_n, dinv, sorted);
    k_gemm1<<<(N_NODES / 16 + 3) / 4, 256, 0, stream>>>(x, W1, dinv, h16);
    k_agg1<<<(N_NODES * 8) / 256 + 1, 256, 0, stream>>>(sorted, boffs_n, (const unsigned*)h16,
                                                        dinv, b1, W2, tp);
    k_agg2<<<(N_NODES + 255) / 256, 256, 0, stream>>>(sorted, boffs_n, tp, dinv, b2, out);
}